// Round 4
// baseline (67.619 us; speedup 1.0000x reference)
//
#include <hip/hip_runtime.h>

#define T_LEN 768
#define TC 32                 // timesteps per chunk
#define NCH (T_LEN / TC)      // 24 chunks (even)
#define SO 65                 // LDS output-plane stride (odd -> conflict-free)

struct Params { const float* p[27]; };

__device__ __forceinline__ float ex2(float x) {
    float r; asm("v_exp_f32 %0, %1" : "=v"(r) : "v"(x)); return r;   // exp2(x)
}
__device__ __forceinline__ float frcp(float x) {
    return __builtin_amdgcn_rcpf(x);                                  // 1/x
}

// One lane owns one FULL row: both channel states live in this lane's
// registers -> the x<->y coupling is a register read (no DPP/LDS on chain).
//
// SHARE path state space: W = c2 - k2*v  (the exp2 argument itself).
//   sigma_self = 1/(1+exp2(W));  synapse drive h_i = -k2*u_i = fma(-G_i,W,R_i)
//   W' = W + r1*h1 + s_own*h2 + s_other*h3   (chain: exp->add->rcp->fma->fma)
//   v  = (c2 - W)/k2 recovered only for the stored x output (off-chain).
template<bool SHARE>
__device__ __forceinline__ void run_all(
    const float4* __restrict__ rowp4, float* __restrict__ out,
    float (*lds_o)[SO], int lane, int r0,
    // input-synapse sigmoids
    float k1x, float c1x, float k1y, float c1y,
    // SHARE: W-space constants
    float mG1x, float R1x, float mG2x, float R2x, float mG3x, float R3x,
    float mG1y, float R1y, float mG2y, float R2y, float mG3y, float R3y,
    float Wx0, float Wy0, float nik2x, float ofsx,
    // fallback: v-space constants
    float k2x, float c2x, float k2y, float c2y,
    float k3xi, float c3xi, float k3yi, float c3yi,
    float A1x, float G1x, float A2x, float G2x, float A3x, float G3x,
    float A1y, float G1y, float A2y, float G2y, float A3y, float G3y)
{
    float Wx = Wx0, Wy = Wy0;       // SHARE state
    float vx = 0.0f, vy = 0.0f;     // fallback state
    float4 bufA[16], bufB[16];      // 32 steps of (a,b) pairs, double-buffered

    auto LOAD = [&](float4 (&b)[16], int c) {
        #pragma unroll
        for (int j = 0; j < 16; ++j) b[j] = rowp4[c * 16 + j];
    };

    auto COMPUTE = [&](float4 (&b)[16], int c) {
        #pragma unroll
        for (int t = 0; t < TC; ++t) {
            float4 q = b[t >> 1];
            float av = (t & 1) ? q.z : q.x;
            float bv = (t & 1) ? q.w : q.y;
            // state-independent input sigmoids (pure ILP, fills chain stalls)
            float r1a = frcp(1.0f + ex2(__builtin_fmaf(-k1x, av, c1x)));
            float r1b = frcp(1.0f + ex2(__builtin_fmaf(-k1y, bv, c1y)));
            float xo;
            if (SHARE) {
                float ex_ = ex2(Wx);
                float ey_ = ex2(Wy);
                float h1x = __builtin_fmaf(mG1x, Wx, R1x);   // parallel with exp
                float h2x = __builtin_fmaf(mG2x, Wx, R2x);
                float h3x = __builtin_fmaf(mG3x, Wx, R3x);
                float h1y = __builtin_fmaf(mG1y, Wy, R1y);
                float h2y = __builtin_fmaf(mG2y, Wy, R2y);
                float h3y = __builtin_fmaf(mG3y, Wy, R3y);
                float sx = frcp(1.0f + ex_);
                float sy = frcp(1.0f + ey_);
                float tx = __builtin_fmaf(r1a, h1x, Wx);     // during rcp
                float ty = __builtin_fmaf(r1b, h1y, Wy);
                tx = __builtin_fmaf(sx, h2x, tx);
                ty = __builtin_fmaf(sy, h2y, ty);
                Wx = __builtin_fmaf(sy, h3x, tx);
                Wy = __builtin_fmaf(sx, h3y, ty);
                xo = __builtin_fmaf(Wx, nik2x, ofsx);        // v_x (off-chain)
            } else {
                float s2x = frcp(1.0f + ex2(__builtin_fmaf(-k2x, vx, c2x)));
                float s2y = frcp(1.0f + ex2(__builtin_fmaf(-k2y, vy, c2y)));
                float s3x = frcp(1.0f + ex2(__builtin_fmaf(-k3xi, vy, c3xi)));
                float s3y = frcp(1.0f + ex2(__builtin_fmaf(-k3yi, vx, c3yi)));
                float u1x = __builtin_fmaf(-vx, G1x, A1x);
                float u2x = __builtin_fmaf(-vx, G2x, A2x);
                float u3x = __builtin_fmaf(-vx, G3x, A3x);
                float u1y = __builtin_fmaf(-vy, G1y, A1y);
                float u2y = __builtin_fmaf(-vy, G2y, A2y);
                float u3y = __builtin_fmaf(-vy, G3y, A3y);
                vx = __builtin_fmaf(s3x, u3x,
                     __builtin_fmaf(s2x, u2x, __builtin_fmaf(r1a, u1x, vx)));
                vy = __builtin_fmaf(s3y, u3y,
                     __builtin_fmaf(s2y, u2y, __builtin_fmaf(r1b, u1y, vy)));
                xo = vx;
            }
            lds_o[t][lane] = xo;
        }
        // Coalesced writeout: 512 float4 = 64 rows x 8 float4.
        #pragma unroll
        for (int k = 0; k < 8; ++k) {
            int f = lane + 64 * k;
            int r = f >> 3, p = f & 7;
            float4 o;
            o.x = lds_o[4 * p + 0][r];
            o.y = lds_o[4 * p + 1][r];
            o.z = lds_o[4 * p + 2][r];
            o.w = lds_o[4 * p + 3][r];
            *(float4*)&out[(size_t)(r0 + r) * T_LEN + c * TC + 4 * p] = o;
        }
    };

    LOAD(bufA, 0);
    for (int cc = 0; cc < NCH; cc += 2) {
        LOAD(bufB, cc + 1);                 // prefetch next chunk into regs
        COMPUTE(bufA, cc);
        if (cc + 2 < NCH) LOAD(bufA, cc + 2);
        COMPUTE(bufB, cc + 1);
    }
}

__global__ __launch_bounds__(64, 1) void cell_kernel(Params P, float* __restrict__ out) {
    __shared__ float lds_o[TC][SO];

    const int lane = (int)threadIdx.x;
    const int r0   = (int)blockIdx.x * 64;

    const float* __restrict__ inp = P.p[0];
    const float capx = P.p[1][0], capy = P.p[2][0];
    const float g_ax = P.p[3][0],  m_ax = P.p[4][0],  s_ax = P.p[5][0],  q_ax = P.p[6][0];
    const float g_by = P.p[7][0],  m_by = P.p[8][0],  s_by = P.p[9][0],  q_by = P.p[10][0];
    const float g_xx = P.p[11][0], m_xx = P.p[12][0], s_xx = P.p[13][0], q_xx = P.p[14][0];
    const float g_xy = P.p[15][0], m_xy = P.p[16][0], s_xy = P.p[17][0], q_xy = P.p[18][0];
    const float g_yx = P.p[19][0], m_yx = P.p[20][0], s_yx = P.p[21][0], q_yx = P.p[22][0];
    const float g_yy = P.p[23][0], m_yy = P.p[24][0], s_yy = P.p[25][0], q_yy = P.p[26][0];

    const float icx = 1.0f / capx, icy = 1.0f / capy;
    const float L2E = 1.44269504088896340736f;

    // Channel x: input ax (pre=a), self xx (pre=x), cross-IN yx (pre=y).
    // Channel y: input by (pre=b), self yy (pre=y), cross-IN xy (pre=x).
    const float k1x = s_ax * L2E, c1x = k1x * m_ax;
    const float k1y = s_by * L2E, c1y = k1y * m_by;
    const float k2x = s_xx * L2E, c2x = k2x * m_xx;
    const float k2y = s_yy * L2E, c2y = k2y * m_yy;
    const float k3xi = s_yx * L2E, c3xi = k3xi * m_yx;   // x's cross-in sigmoid
    const float k3yi = s_xy * L2E, c3yi = k3yi * m_xy;   // y's cross-in sigmoid

    const float A1x = g_ax * q_ax * icx, G1x = g_ax * icx;
    const float A2x = g_xx * q_xx * icx, G2x = g_xx * icx;
    const float A3x = g_yx * q_yx * icx, G3x = g_yx * icx;
    const float A1y = g_by * q_by * icy, G1y = g_by * icy;
    const float A2y = g_yy * q_yy * icy, G2y = g_yy * icy;
    const float A3y = g_xy * q_xy * icy, G3y = g_xy * icy;

    // W-space constants: h_i = fma(-G_i, W, R_i) with R_i = G_i*c2 - k2*A_i.
    const float R1x = __builtin_fmaf(G1x, c2x, -k2x * A1x);
    const float R2x = __builtin_fmaf(G2x, c2x, -k2x * A2x);
    const float R3x = __builtin_fmaf(G3x, c2x, -k2x * A3x);
    const float R1y = __builtin_fmaf(G1y, c2y, -k2y * A1y);
    const float R2y = __builtin_fmaf(G2y, c2y, -k2y * A2y);
    const float R3y = __builtin_fmaf(G3y, c2y, -k2y * A3y);
    const float nik2x = -1.0f / k2x;          // for x-output recovery
    const float ofsx  = c2x / k2x;

    // Share valid when each channel's cross-IN sigmoid == the OTHER channel's
    // self sigmoid: sig_yx(y) == sig_yy(y) and sig_xy(x) == sig_xx(x).
    const bool share = (s_yx == s_yy) && (m_yx == m_yy) &&
                       (s_xy == s_xx) && (m_xy == m_xx) &&
                       (s_xx != 0.0f) && (s_yy != 0.0f);

    const float4* __restrict__ rowp4 =
        (const float4*)inp + (size_t)(r0 + lane) * (T_LEN * 2 / 4);   // 384 f4/row

    if (share)
        run_all<true >(rowp4, out, lds_o, lane, r0,
                       k1x, c1x, k1y, c1y,
                       -G1x, R1x, -G2x, R2x, -G3x, R3x,
                       -G1y, R1y, -G2y, R2y, -G3y, R3y,
                       c2x, c2y, nik2x, ofsx,
                       k2x, c2x, k2y, c2y, k3xi, c3xi, k3yi, c3yi,
                       A1x, G1x, A2x, G2x, A3x, G3x,
                       A1y, G1y, A2y, G2y, A3y, G3y);
    else
        run_all<false>(rowp4, out, lds_o, lane, r0,
                       k1x, c1x, k1y, c1y,
                       -G1x, R1x, -G2x, R2x, -G3x, R3x,
                       -G1y, R1y, -G2y, R2y, -G3y, R3y,
                       c2x, c2y, nik2x, ofsx,
                       k2x, c2x, k2y, c2y, k3xi, c3xi, k3yi, c3yi,
                       A1x, G1x, A2x, G2x, A3x, G3x,
                       A1y, G1y, A2y, G2y, A3y, G3y);
}

extern "C" void kernel_launch(void* const* d_in, const int* in_sizes, int n_in,
                              void* d_out, int out_size, void* d_ws, size_t ws_size,
                              hipStream_t stream) {
    (void)d_ws; (void)ws_size; (void)out_size; (void)n_in;
    Params P;
    for (int i = 0; i < 27; ++i) P.p[i] = (const float*)d_in[i];
    float* out = (float*)d_out;
    const int B = in_sizes[0] / (T_LEN * 2);   // 16384
    dim3 grid(B / 64);                         // 256 blocks x 64 threads (1 wave)
    cell_kernel<<<grid, dim3(64), 0, stream>>>(P, out);
}

// Round 5
// 45.835 us; speedup vs baseline: 1.4753x; 1.4753x over previous
//
#include <hip/hip_runtime.h>

#define T_LEN 768
#define TC 32                 // timesteps per chunk
#define NCH (T_LEN / TC)      // 24 chunks
#define RPB 32                // rows per block
#define R1S 36                // r1buf row stride (floats): 16B-aligned, low-conflict
#define OS  66                // lds_o stride: 2-way max

struct Params { const float* p[27]; };

__device__ __forceinline__ float ex2(float x){ float r; asm("v_exp_f32 %0, %1":"=v"(r):"v"(x)); return r; }
__device__ __forceinline__ float frcp(float x){ return __builtin_amdgcn_rcpf(x); }
__device__ __forceinline__ float dpp_xor1(float x){
    // lane <-> lane^1 swap, quad_perm [1,0,3,2]; pure VALU
    return __int_as_float(__builtin_amdgcn_mov_dpp(__float_as_int(x),0xB1,0xF,0xF,true));
}
__device__ __forceinline__ float psig(float v, float k, float c){
    return frcp(1.0f + ex2(__builtin_fmaf(-k, v, c)));
}

// Block = 128 threads: wave0 = serial consumer (2 lanes/row x 32 rows),
// wave1 = producer (input sigmoids + global loads + output drain).
__global__ __launch_bounds__(128, 1) void cell_kernel(Params P, float* __restrict__ out) {
    __shared__ float r1buf[2][64][R1S];   // [buf][consumer-lane][t]
    __shared__ float lds_o[2][TC][OS];    // [buf][t][consumer-lane]

    const int tid = (int)threadIdx.x;
    const int r0  = (int)blockIdx.x * RPB;
    const bool isProd = tid >= 64;
    const int l = tid & 63;

    const float* __restrict__ inp = P.p[0];
    const float capx = P.p[1][0], capy = P.p[2][0];
    const float g_ax = P.p[3][0],  m_ax = P.p[4][0],  s_ax = P.p[5][0],  q_ax = P.p[6][0];
    const float g_by = P.p[7][0],  m_by = P.p[8][0],  s_by = P.p[9][0],  q_by = P.p[10][0];
    const float g_xx = P.p[11][0], m_xx = P.p[12][0], s_xx = P.p[13][0], q_xx = P.p[14][0];
    const float g_xy = P.p[15][0], m_xy = P.p[16][0], s_xy = P.p[17][0], q_xy = P.p[18][0];
    const float g_yx = P.p[19][0], m_yx = P.p[20][0], s_yx = P.p[21][0], q_yx = P.p[22][0];
    const float g_yy = P.p[23][0], m_yy = P.p[24][0], s_yy = P.p[25][0], q_yy = P.p[26][0];

    const float icx = 1.0f / capx, icy = 1.0f / capy;
    const float L2E = 1.44269504088896340736f;

    // input-synapse sigmoids (producer)
    const float k1x = s_ax * L2E, c1x = k1x * m_ax;
    const float k1y = s_by * L2E, c1y = k1y * m_by;

    // consumer role constants (even lane = x-channel, odd = y-channel)
    const bool isX = (l & 1) == 0;
    const float k2r = (isX ? s_xx : s_yy) * L2E;              // self sigmoid
    const float c2r = k2r * (isX ? m_xx : m_yy);
    const float k3r = (isX ? s_xy : s_yx) * L2E;              // cross-OUT sigmoid (general path)
    const float c3r = k3r * (isX ? m_xy : m_yx);
    const float icr = isX ? icx : icy;
    const float A1r = (isX ? g_ax * q_ax : g_by * q_by) * icr, G1r = (isX ? g_ax : g_by) * icr;
    const float A2r = (isX ? g_xx * q_xx : g_yy * q_yy) * icr, G2r = (isX ? g_xx : g_yy) * icr;
    const float A3r = (isX ? g_yx * q_yx : g_xy * q_xy) * icr, G3r = (isX ? g_yx : g_xy) * icr; // cross-IN

    // W-space (share path): W = c2 - k2*v; h_i = fma(-G_i, W, R_i); W' = W + sum r_i h_i
    const float R1r = __builtin_fmaf(G1r, c2r, -k2r * A1r);
    const float R2r = __builtin_fmaf(G2r, c2r, -k2r * A2r);
    const float R3r = __builtin_fmaf(G3r, c2r, -k2r * A3r);
    const float nik2r = -1.0f / k2r, ofsr = c2r / k2r;        // v recovery

    // 2^d poly: 2^d = 1 + d*(P1 + d*(P2 + d*P3))
    const float P1 = 0.69314718056f, P2 = 0.2402265070f, P3 = 0.0555041087f;

    // share: partner's self sigma can stand in for the cross-IN sigma
    const bool share = (s_yx == s_yy) && (m_yx == m_yy) &&
                       (s_xy == s_xx) && (m_xy == m_xx) &&
                       (s_xx != 0.0f) && (s_yy != 0.0f);

    const float4* __restrict__ in4 = (const float4*)inp;      // row stride 384 f4

    // ---- consumer state ----
    float W = c2r;            // share path (v=0 -> W=c2)
    float E = 0.0f, r = 0.0f;
    float v = 0.0f;           // general path

    // ---- prologue: producer fills r1buf[0] for chunk 0 ----
    if (isProd) {
        float4 pin[8];
        #pragma unroll
        for (int k = 0; k < 8; ++k) { int idx = l + 64*k; int rr_ = idx >> 4, q = idx & 15;
            pin[k] = in4[(size_t)(r0 + rr_) * 384 + q]; }
        #pragma unroll
        for (int k = 0; k < 8; ++k) { int idx = l + 64*k; int rr_ = idx >> 4, q = idx & 15;
            float* rA = &r1buf[0][2*rr_][0]; float* rB = &r1buf[0][2*rr_ + 1][0];
            rA[2*q]     = psig(pin[k].x, k1x, c1x);
            rB[2*q]     = psig(pin[k].y, k1y, c1y);
            rA[2*q + 1] = psig(pin[k].z, k1x, c1x);
            rB[2*q + 1] = psig(pin[k].w, k1y, c1y); }
    }
    __syncthreads();

    for (int c = 0; c < NCH; ++c) {
        if (isProd) {
            // 1) issue next chunk's global loads (latency hidden under drain)
            float4 pin[8];
            if (c + 1 < NCH) {
                #pragma unroll
                for (int k = 0; k < 8; ++k) { int idx = l + 64*k; int rr_ = idx >> 4, q = idx & 15;
                    pin[k] = in4[(size_t)(r0 + rr_) * 384 + (c + 1) * 16 + q]; }
            }
            // 2) drain chunk c-1 outputs to global
            if (c >= 1) {
                const int buf = (c - 1) & 1;
                #pragma unroll
                for (int k = 0; k < 4; ++k) { int f = l + 64*k; int rr_ = f >> 3, p = f & 7;
                    float4 o;
                    o.x = lds_o[buf][4*p + 0][2*rr_];
                    o.y = lds_o[buf][4*p + 1][2*rr_];
                    o.z = lds_o[buf][4*p + 2][2*rr_];
                    o.w = lds_o[buf][4*p + 3][2*rr_];
                    *(float4*)&out[(size_t)(r0 + rr_) * T_LEN + (c - 1) * TC + 4*p] = o; }
            }
            // 3) input sigmoids for chunk c+1 -> r1buf
            if (c + 1 < NCH) {
                const int buf = (c + 1) & 1;
                #pragma unroll
                for (int k = 0; k < 8; ++k) { int idx = l + 64*k; int rr_ = idx >> 4, q = idx & 15;
                    float* rA = &r1buf[buf][2*rr_][0]; float* rB = &r1buf[buf][2*rr_ + 1][0];
                    rA[2*q]     = psig(pin[k].x, k1x, c1x);
                    rB[2*q]     = psig(pin[k].y, k1y, c1y);
                    rA[2*q + 1] = psig(pin[k].z, k1x, c1x);
                    rB[2*q + 1] = psig(pin[k].w, k1y, c1y); }
            }
        } else {
            const int buf = c & 1;
            // prefetch this chunk's input sigmoids (b128, 16B-aligned rows)
            float rr[TC];
            #pragma unroll
            for (int j = 0; j < 8; ++j) {
                float4 v4 = *(const float4*)&r1buf[buf][l][4*j];
                rr[4*j] = v4.x; rr[4*j+1] = v4.y; rr[4*j+2] = v4.z; rr[4*j+3] = v4.w;
            }
            if (share) {
                // chunk-start recalibration: exact E and sigma (kills drift)
                E = ex2(W);
                r = frcp(1.0f + E);
                #pragma unroll
                for (int t = 0; t < TC; ++t) {
                    // sigma = 1/(1+E) via 2 Newton steps seeded from previous sigma
                    float d  = 1.0f + E;
                    float nt = __builtin_fmaf(-d, r, 2.0f); r = r * nt;
                    nt       = __builtin_fmaf(-d, r, 2.0f); r = r * nt;
                    float rp = dpp_xor1(r);                    // partner's sigma
                    float h1 = __builtin_fmaf(-G1r, W, R1r);
                    float h2 = __builtin_fmaf(-G2r, W, R2r);
                    float h3 = __builtin_fmaf(-G3r, W, R3r);
                    float s1 = __builtin_fmaf(rr[t], h1, W);
                    float s2 = __builtin_fmaf(r,     h2, s1);
                    float Wn = __builtin_fmaf(rp,    h3, s2);
                    float dl = Wn - W;
                    // E' = E * 2^dl  (degree-3 poly, |dl| <~ 0.3)
                    float qq = __builtin_fmaf(P3, dl, P2);
                    qq       = __builtin_fmaf(qq, dl, P1);
                    E        = __builtin_fmaf(E * dl, qq, E);
                    W = Wn;
                    lds_o[buf][t][l] = __builtin_fmaf(W, nik2r, ofsr);   // v (x in even lanes)
                }
            } else {
                #pragma unroll
                for (int t = 0; t < TC; ++t) {
                    float s2 = psig(v, k2r, c2r);              // self sigma
                    float s3 = psig(v, k3r, c3r);              // own cross-OUT sigma
                    float rp = dpp_xor1(s3);                   // partner's cross sigma
                    float u1 = __builtin_fmaf(-v, G1r, A1r);
                    float u2 = __builtin_fmaf(-v, G2r, A2r);
                    float u3 = __builtin_fmaf(-v, G3r, A3r);
                    v = __builtin_fmaf(rp, u3,
                        __builtin_fmaf(s2, u2,
                        __builtin_fmaf(rr[t], u1, v)));
                    lds_o[buf][t][l] = v;
                }
            }
        }
        __syncthreads();
    }

    // final drain: chunk NCH-1
    if (isProd) {
        const int buf = (NCH - 1) & 1;
        #pragma unroll
        for (int k = 0; k < 4; ++k) { int f = l + 64*k; int rr_ = f >> 3, p = f & 7;
            float4 o;
            o.x = lds_o[buf][4*p + 0][2*rr_];
            o.y = lds_o[buf][4*p + 1][2*rr_];
            o.z = lds_o[buf][4*p + 2][2*rr_];
            o.w = lds_o[buf][4*p + 3][2*rr_];
            *(float4*)&out[(size_t)(r0 + rr_) * T_LEN + (NCH - 1) * TC + 4*p] = o; }
    }
}

extern "C" void kernel_launch(void* const* d_in, const int* in_sizes, int n_in,
                              void* d_out, int out_size, void* d_ws, size_t ws_size,
                              hipStream_t stream) {
    (void)d_ws; (void)ws_size; (void)out_size; (void)n_in;
    Params P;
    for (int i = 0; i < 27; ++i) P.p[i] = (const float*)d_in[i];
    float* out = (float*)d_out;
    const int B = in_sizes[0] / (T_LEN * 2);   // 16384
    dim3 grid(B / RPB);                        // 512 blocks x 128 threads (2 waves)
    cell_kernel<<<grid, dim3(128), 0, stream>>>(P, out);
}